// Round 1
// 175.493 us; speedup vs baseline: 1.0046x; 1.0046x over previous
//
#include <hip/hip_runtime.h>
#include <math.h>

// Problem dims (fixed by reference)
#define BATCH 32
#define CH    1024     // C == P
#define NPix  784      // H*W = 28*28
#define MMOD  4        // M models, Q == 1
#define NZB   32       // k_nz blocks per batch sample (chunk-groups)
#define CPB   2        // 16-channel chunks per k_nz block (NZB*CPB*PPC == CH)
#define PPC   16       // channels per chunk
#define K1B   256      // k_nz block: 4 waves
#define NF4   196      // float4 per 784-pixel row
#define T2    832      // 13 waves: covers 784 pixels

__device__ __forceinline__ float wave_reduce(float s) {
    #pragma unroll
    for (int off = 32; off; off >>= 1) s += __shfl_down(s, off, 64);
    return s;
}

// Wave64 sum on the VALU pipe (DPP; verified correct in prior session R6).
// Full sum lands in lane 63.
__device__ __forceinline__ float dpp_wave_sum(float v) {
    int x;
    x = __builtin_amdgcn_update_dpp(0, __builtin_bit_cast(int, v), 0x111, 0xf, 0xf, true);
    v += __builtin_bit_cast(float, x);
    x = __builtin_amdgcn_update_dpp(0, __builtin_bit_cast(int, v), 0x112, 0xf, 0xf, true);
    v += __builtin_bit_cast(float, x);
    x = __builtin_amdgcn_update_dpp(0, __builtin_bit_cast(int, v), 0x114, 0xf, 0xf, true);
    v += __builtin_bit_cast(float, x);
    x = __builtin_amdgcn_update_dpp(0, __builtin_bit_cast(int, v), 0x118, 0xf, 0xf, true);
    v += __builtin_bit_cast(float, x);
    x = __builtin_amdgcn_update_dpp(0, __builtin_bit_cast(int, v), 0x142, 0xa, 0xf, true);
    v += __builtin_bit_cast(float, x);
    x = __builtin_amdgcn_update_dpp(0, __builtin_bit_cast(int, v), 0x143, 0xc, 0xf, true);
    v += __builtin_bit_cast(float, x);
    return v;
}

// Single-pass norms + z-partials. This round: 32 channels per block in TWO
// serial 16-channel chunks (xv[16] register footprint unchanged), z-partials
// a0..a3 accumulated ACROSS chunks -> zpart shrinks 25.7 MB -> 12.9 MB
// (halves the round-trip to k_gh). Grid 1024 = exactly 4 blocks/CU.
// Barrier note: per chunk [load][dpp][sq_l wr][sync][wl4 wr][sync][B: rd wl4].
// Next chunk's sq_l writes race nothing (sq_l readers fenced by sync2);
// next chunk's wl4 writes are after ITS sync1, which all phase-B readers
// must reach first. Two barriers per chunk suffice.
__global__ __launch_bounds__(K1B) void k_nz(const float* __restrict__ x,
                                            const float* __restrict__ Wm,
                                            float* __restrict__ inv_norm,
                                            float* __restrict__ zpart) {
    __shared__ float sq_l[PPC][4];
    __shared__ float4 wl4[PPC];
    const int blk = blockIdx.x;           // 0..1023
    const int b   = blk >> 5;             // / NZB
    const int pcg = blk & (NZB - 1);
    const int t = threadIdx.x;
    const int wv = t >> 6, lane = t & 63;
    const bool act = (t < NF4);
    const int tt = act ? t : 0;

    float4 a0 = {0,0,0,0}, a1 = {0,0,0,0}, a2 = {0,0,0,0}, a3 = {0,0,0,0};

    #pragma unroll
    for (int c = 0; c < CPB; c++) {
        const int ch0 = pcg * (CPB * PPC) + c * PPC;   // first channel of chunk
        const float4* xb4 = (const float4*)(x + ((size_t)b * CH + ch0) * NPix);

        float4 xv[PPC];
        #pragma unroll
        for (int pp = 0; pp < PPC; pp++) xv[pp] = xb4[pp * NF4 + tt];  // 16B/lane

        #pragma unroll
        for (int pp = 0; pp < PPC; pp++) {
            float4 v = xv[pp];
            float s = act ? (v.x*v.x + v.y*v.y + v.z*v.z + v.w*v.w) : 0.f;
            s = dpp_wave_sum(s);
            if (lane == 63) sq_l[pp][wv] = s;
        }
        __syncthreads();

        if (t < PPC) {
            const float s = sq_l[t][0] + sq_l[t][1] + sq_l[t][2] + sq_l[t][3];
            const float inv = 1.f / fmaxf(sqrtf(s), 1e-10f);
            const int p = ch0 + t;
            inv_norm[b * CH + p] = inv;
            float4 w4;
            w4.x = Wm[0 * CH + p] * inv;
            w4.y = Wm[1 * CH + p] * inv;
            w4.z = Wm[2 * CH + p] * inv;
            w4.w = Wm[3 * CH + p] * inv;
            wl4[t] = w4;
        }
        __syncthreads();

        if (act) {
            #pragma unroll
            for (int pp = 0; pp < PPC; pp++) {
                const float4 w = wl4[pp];     // ds_read_b128, same-addr broadcast
                const float4 v = xv[pp];
                a0.x += w.x*v.x; a0.y += w.x*v.y; a0.z += w.x*v.z; a0.w += w.x*v.w;
                a1.x += w.y*v.x; a1.y += w.y*v.y; a1.z += w.y*v.z; a1.w += w.y*v.w;
                a2.x += w.z*v.x; a2.y += w.z*v.y; a2.z += w.z*v.z; a2.w += w.z*v.w;
                a3.x += w.w*v.x; a3.y += w.w*v.y; a3.z += w.w*v.z; a3.w += w.w*v.w;
            }
        }
    }

    if (act) {
        float4* zp = (float4*)(zpart + ((size_t)blk * MMOD) * NPix);
        zp[0 * NF4 + t] = a0;
        zp[1 * NF4 + t] = a1;
        zp[2 * NF4 + t] = a2;
        zp[3 * NF4 + t] = a3;
    }
}

// Per (b,m) block (grid 128): z = sum over 32 chunk-groups, g = sigmoid(z),
// s2 = block-reduced sum g^2. Half the loads (32/thread) vs last round;
// fully unrolled for max loads-in-flight.
__global__ __launch_bounds__(T2) void k_gh(const float* __restrict__ zpart,
                                           float* __restrict__ g_out,
                                           float* __restrict__ s2g) {
    __shared__ float red[13];
    const int blk = blockIdx.x;
    const int b = blk >> 2;
    const int m = blk & 3;
    const int t = threadIdx.x;
    const int wv = t >> 6, lane = t & 63;
    const bool act = (t < NPix);

    float z = 0.f;
    if (act) {
        #pragma unroll
        for (int pc = 0; pc < NZB; pc++)
            z += zpart[(((size_t)(b * NZB + pc)) * MMOD + m) * NPix + t];
    }
    const float g = act ? 1.f / (1.f + expf(-z)) : 0.f;
    float s = wave_reduce(g * g);
    if (lane == 0) red[wv] = s;
    __syncthreads();
    if (t == 0) {
        float ss = 0.f;
        #pragma unroll
        for (int w = 0; w < 13; w++) ss += red[w];
        s2g[blk] = fmaxf(ss, 1e-30f);
    }
    if (act) g_out[(size_t)blk * NPix + t] = g;
}

// h[b,n] = sum_m g[b,m,n] / s2[b,m]. Grid 128 (b x pixel-quarter) instead of
// 32 — was a 1/8-machine latency bubble.
__global__ __launch_bounds__(256) void k_h(const float* __restrict__ g_out,
                                           const float* __restrict__ s2g,
                                           float* __restrict__ h) {
    const int b = blockIdx.x >> 2;
    const int q = blockIdx.x & 3;
    const int t = threadIdx.x;
    if (t < NF4) {
        const int n = q * NF4 + t;
        float hv = 0.f;
        #pragma unroll
        for (int m = 0; m < MMOD; m++)
            hv += g_out[(size_t)(b * MMOD + m) * NPix + n] / s2g[b * MMOD + m];
        h[(size_t)b * NPix + n] = hv;
    }
}

// out[b,p] = inv_norm[b,p] * dot(x[b,p,:], h[b,:]). One wave per row,
// float4 throughout; x is L3-resident after k_nz.
__global__ __launch_bounds__(256) void k_out(const float* __restrict__ x,
                                             const float* __restrict__ h,
                                             const float* __restrict__ inv_norm,
                                             float* __restrict__ out) {
    const int r = blockIdx.x * 4 + (threadIdx.x >> 6);  // r in [0, 32768)
    const int lane = threadIdx.x & 63;
    const int b = r >> 10;
    const float4* x4 = (const float4*)(x + (size_t)r * NPix);
    const float4* h4 = (const float4*)(h + (size_t)b * NPix);
    float s = 0.f;
    #pragma unroll
    for (int i = 0; i < 3; i++) {
        float4 xv = x4[i * 64 + lane];
        float4 hv = h4[i * 64 + lane];
        s += xv.x*hv.x + xv.y*hv.y + xv.z*hv.z + xv.w*hv.w;
    }
    if (lane < 4) {
        float4 xv = x4[192 + lane];
        float4 hv = h4[192 + lane];
        s += xv.x*hv.x + xv.y*hv.y + xv.z*hv.z + xv.w*hv.w;
    }
    s = wave_reduce(s);
    if (lane == 0) {
        float v = s * inv_norm[r];
        // nan_to_num semantics: nan->0, +/-inf -> +/-FLT_MAX
        if (!(v == v)) v = 0.f;
        v = fminf(fmaxf(v, -3.402823466e+38f), 3.402823466e+38f);
        out[r] = v;
    }
}

extern "C" void kernel_launch(void* const* d_in, const int* in_sizes, int n_in,
                              void* d_out, int out_size, void* d_ws, size_t ws_size,
                              hipStream_t stream) {
    const float* x  = (const float*)d_in[0];   // [32,1024,28,28]
    const float* Wm = (const float*)d_in[1];   // [4,1,1024]
    float* out = (float*)d_out;                // [32,1024]
    float* wsf = (float*)d_ws;

    float* inv_norm = wsf;                                        // 32768 floats
    float* zpart    = inv_norm + BATCH * CH;                      // 1024*4*784 = 3211264 floats
    float* g_out    = zpart + (size_t)BATCH * NZB * MMOD * NPix;  // 32*4*784 = 100352 floats
    float* s2g      = g_out + (size_t)BATCH * MMOD * NPix;        // 128 floats
    float* h        = s2g + BATCH * MMOD;                         // 25088 floats

    k_nz<<<BATCH * NZB, K1B, 0, stream>>>(x, Wm, inv_norm, zpart);
    k_gh<<<BATCH * MMOD, T2, 0, stream>>>(zpart, g_out, s2g);
    k_h<<<BATCH * MMOD, 256, 0, stream>>>(g_out, s2g, h);
    k_out<<<BATCH * CH / 4, 256, 0, stream>>>(x, h, inv_norm, out);
}